// Round 8
// baseline (2369.814 us; speedup 1.0000x reference)
//
#include <hip/hip_runtime.h>
#include <cstddef>

// TransitionDown: B=16 clouds, P=4096 pts, S=1024 fps samples, K=16 knn,
// IN_F=256, OUT_F=512.
//
// TWO static flag-gated kernels (persistent-worker design of r6/r7 abandoned
// after two unexplained failures; static gating passed r3/r4/r5).
//
// K1 td_main (84KB LDS pad -> 1 block/CU; FPS CUs private, r3-proven):
//   [0,16)      FPS (round-0 core) + chunk publish every 128 samples
//   [16,1040)   MLP GEMM fp32 -> h bf16
//   [1040,1936) KNN chunks 0..6: 128q x 512c blocks (gate: FPS chunk c)
//   [1936,2192) BN partial sums (gate: gemm done)
//   [2192]      BN finalize (gate: stats done)
//   [2193,2833) merge chunks 0..4, 16q/block (gate: chunk KNN done)
//   [2833,3473) maxpool chunks 0..4, 16q/block (gate: merge + bnfin)
//   All shadow work fits 240 CUs x 620us; k1 wall ~= FPS time.
// K2 td_tail (~35KB LDS -> 2 blocks/CU): only FPS-end-dependent work:
//   [0,256)     KNN chunk 7: 128q x 256c blocks (no gate: k1 done)
//   [256,640)   merge chunks 5,6,7 (gate only c=7 on KNNDONE)
//   [640,1024)  maxpool chunks 5,6,7 (gate: MERGEDONE)
// Producers strictly below consumers in block index in each kernel =>
// deadlock-free under in-order dispatch; k2 is fully resident (1024 blocks).

#define TD_B   16
#define TD_P   4096
#define TD_S   1024
#define TD_K   16
#define TD_INF 256
#define TD_OUTF 512

// ---- flag indices (workspace ints, zeroed per launch) ----
#define F_GEMMDONE   3    // 1024
#define F_STATSDONE  5    // 256
#define F_BNFIN      7    // 1
#define F_CHUNKREADY 8    // +c (8): clouds that published chunk c (target 16)
#define F_KNNDONE    24   // +c (8): target 128 (c<7) / 256 (c==7)
#define F_MERGEDONE  40   // +c (8): target 128

typedef __attribute__((ext_vector_type(8))) _Float16 half8;
typedef __attribute__((ext_vector_type(4))) float    f32x4;
typedef __attribute__((ext_vector_type(2))) float    v2f;

__device__ __forceinline__ unsigned short f2bf(float x) {
    unsigned u = __float_as_uint(x);
    unsigned r = (u + 0x7fffu + ((u >> 16) & 1u)) >> 16;   // RNE
    return (unsigned short)r;
}

__device__ __forceinline__ int ld_acq(const int* p) {
    return __hip_atomic_load(p, __ATOMIC_ACQUIRE, __HIP_MEMORY_SCOPE_AGENT);
}
__device__ __forceinline__ void st_rel(int* p, int v) {
    __hip_atomic_store(p, v, __ATOMIC_RELEASE, __HIP_MEMORY_SCOPE_AGENT);
}
__device__ __forceinline__ void add_rel(int* p, int v) {
    __hip_atomic_fetch_add(p, v, __ATOMIC_RELEASE, __HIP_MEMORY_SCOPE_AGENT);
}

struct FpsSm {
    float4 p4[TD_P];                 // 64 KB
    int    sel[TD_S];                // 4 KB
    unsigned long long kw[2][4];     // parity-buffered per-wave argmax keys
};
struct GemmSm {
    float As[16 * 260];
    float Bs[16 * 128];
};
struct KnnSm {
    union {
        _Float16 x[2][32][264];      // [hi/lo][c][k], row pad 8 halfs (33792 B)
        float    dt[128][33];        // aliased after MFMA
    } u;
    float QQs[128];
    int   QR[128];
    float xxs[32];
};
struct MergeSm {
    float ld[16][258];               // up to 256 entries, +2 pad
    int   li[16][258];
};
struct MaxpSm { int nbr[256]; };
union SmU1 {                         // k1: pad forces 1 block/CU (FPS privacy)
    FpsSm f; GemmSm g; KnnSm k; MergeSm m; MaxpSm mp;
    char pad_[84000];
};
union SmU2 {                         // k2: ~34.9 KB -> 2 blocks/CU
    KnnSm k; MergeSm m; MaxpSm mp;
};

// One level of a wave64 max-reduce on a positive-double key via paired 32-bit
// DPP + v_max_f64 (key hi=fp32 bits of min_d, lo=~idx; positive finite
// doubles => fmax == bitwise u64 max, tie -> lowest idx).
#define TD_DPPSTEPD(kd_, ctl, bc)                                                       \
    {                                                                                   \
        long long ki_ = __double_as_longlong(kd_);                                      \
        unsigned yh_ = (unsigned)__builtin_amdgcn_update_dpp(                           \
            0, (int)((unsigned long long)ki_ >> 32), (ctl), 0xf, 0xf, (bc));            \
        unsigned yl_ = (unsigned)__builtin_amdgcn_update_dpp(                           \
            0, (int)(unsigned)(unsigned long long)ki_, (ctl), 0xf, 0xf, (bc));          \
        kd_ = fmax(kd_, __hiloint2double((int)yh_, (int)yl_));                          \
    }

// ---- shared device bodies (templated on the SM union used) -----------------

template <typename SM>
__device__ __forceinline__ void knn_body(
        SM& sm, const float* __restrict__ feat, const int* __restrict__ FPSI,
        float* __restrict__ PD, int* __restrict__ PI, int t,
        int qbase, int segbase, int nct, int slotb) {
    if (t < 128) sm.k.QR[t] = FPSI[qbase + t];
    __syncthreads();

    const int w = t >> 6, lane = t & 63;
    const int m = lane & 15, quad = lane >> 4;

    // Q fragments: wave w owns queries [w*16, w*16+16)
    half8 qh[8], ql[8];
    {
        const float* qp = feat + (size_t)sm.k.QR[w * 16 + m] * 256;
        float qq2 = 0.0f;
#pragma unroll
        for (int ks = 0; ks < 8; ++ks) {
            float4 f0 = *(const float4*)(qp + ks * 32 + quad * 8);
            float4 f1 = *(const float4*)(qp + ks * 32 + quad * 8 + 4);
            float fv[8] = {f0.x, f0.y, f0.z, f0.w, f1.x, f1.y, f1.z, f1.w};
            half8 h, l;
#pragma unroll
            for (int j = 0; j < 8; ++j) {
                _Float16 hv = (_Float16)fv[j];
                h[j] = hv;
                l[j] = (_Float16)(fv[j] - (float)hv);
                qq2 = fmaf(fv[j], fv[j], qq2);
            }
            qh[ks] = h; ql[ks] = l;
        }
        qq2 += __shfl_xor(qq2, 16, 64);
        qq2 += __shfl_xor(qq2, 32, 64);
        if (quad == 0) sm.k.QQs[w * 16 + m] = qq2;
    }

    float sd[16]; int si[16];
#pragma unroll
    for (int rr = 0; rr < 16; ++rr) { sd[rr] = __builtin_inff(); si[rr] = 0x7fffffff; }

    const int xrow = t >> 4, part = t & 15;

    for (int ct = 0; ct < nct; ++ct) {
        __syncthreads();   // selection done reading dt (aliases x)
        // stage 32 cands x 256k fp32->fp16 hi/lo + cand norms
        {
            const float* xp = feat + (size_t)(segbase + ct * 32 + xrow) * 256 + part * 16;
            float4 f0 = *(const float4*)(xp);
            float4 f1 = *(const float4*)(xp + 4);
            float4 f2 = *(const float4*)(xp + 8);
            float4 f3 = *(const float4*)(xp + 12);
            float fv[16] = {f0.x, f0.y, f0.z, f0.w, f1.x, f1.y, f1.z, f1.w,
                            f2.x, f2.y, f2.z, f2.w, f3.x, f3.y, f3.z, f3.w};
            half8 h0, h1, l0, l1;
            float cn = 0.0f;
#pragma unroll
            for (int j = 0; j < 8; ++j) {
                _Float16 hv = (_Float16)fv[j];
                h0[j] = hv; l0[j] = (_Float16)(fv[j] - (float)hv);
                cn = fmaf(fv[j], fv[j], cn);
            }
#pragma unroll
            for (int j = 0; j < 8; ++j) {
                float v = fv[8 + j];
                _Float16 hv = (_Float16)v;
                h1[j] = hv; l1[j] = (_Float16)(v - (float)hv);
                cn = fmaf(v, v, cn);
            }
            *(half8*)&sm.k.u.x[0][xrow][part * 16]     = h0;
            *(half8*)&sm.k.u.x[0][xrow][part * 16 + 8] = h1;
            *(half8*)&sm.k.u.x[1][xrow][part * 16]     = l0;
            *(half8*)&sm.k.u.x[1][xrow][part * 16 + 8] = l1;
            cn += __shfl_xor(cn, 1, 64);
            cn += __shfl_xor(cn, 2, 64);
            cn += __shfl_xor(cn, 4, 64);
            cn += __shfl_xor(cn, 8, 64);
            if (part == 0) sm.k.xxs[xrow] = cn;
        }
        __syncthreads();
        // MFMA: 4 chains = [cand-half][ks-parity]
        f32x4 a00 = (f32x4)0.0f, a01 = (f32x4)0.0f;
        f32x4 a10 = (f32x4)0.0f, a11 = (f32x4)0.0f;
#pragma unroll
        for (int k2 = 0; k2 < 4; ++k2) {
            const int ka = 2 * k2, kb2 = 2 * k2 + 1;
            half8 xh0a = *(half8*)&sm.k.u.x[0][m][ka * 32 + quad * 8];
            half8 xl0a = *(half8*)&sm.k.u.x[1][m][ka * 32 + quad * 8];
            half8 xh1a = *(half8*)&sm.k.u.x[0][16 + m][ka * 32 + quad * 8];
            half8 xl1a = *(half8*)&sm.k.u.x[1][16 + m][ka * 32 + quad * 8];
            half8 xh0b = *(half8*)&sm.k.u.x[0][m][kb2 * 32 + quad * 8];
            half8 xl0b = *(half8*)&sm.k.u.x[1][m][kb2 * 32 + quad * 8];
            half8 xh1b = *(half8*)&sm.k.u.x[0][16 + m][kb2 * 32 + quad * 8];
            half8 xl1b = *(half8*)&sm.k.u.x[1][16 + m][kb2 * 32 + quad * 8];
            a00 = __builtin_amdgcn_mfma_f32_16x16x32_f16(ql[ka],  xh0a, a00, 0, 0, 0);
            a10 = __builtin_amdgcn_mfma_f32_16x16x32_f16(ql[ka],  xh1a, a10, 0, 0, 0);
            a01 = __builtin_amdgcn_mfma_f32_16x16x32_f16(ql[kb2], xh0b, a01, 0, 0, 0);
            a11 = __builtin_amdgcn_mfma_f32_16x16x32_f16(ql[kb2], xh1b, a11, 0, 0, 0);
            a00 = __builtin_amdgcn_mfma_f32_16x16x32_f16(qh[ka],  xl0a, a00, 0, 0, 0);
            a10 = __builtin_amdgcn_mfma_f32_16x16x32_f16(qh[ka],  xl1a, a10, 0, 0, 0);
            a01 = __builtin_amdgcn_mfma_f32_16x16x32_f16(qh[kb2], xl0b, a01, 0, 0, 0);
            a11 = __builtin_amdgcn_mfma_f32_16x16x32_f16(qh[kb2], xl1b, a11, 0, 0, 0);
            a00 = __builtin_amdgcn_mfma_f32_16x16x32_f16(qh[ka],  xh0a, a00, 0, 0, 0);
            a10 = __builtin_amdgcn_mfma_f32_16x16x32_f16(qh[ka],  xh1a, a10, 0, 0, 0);
            a01 = __builtin_amdgcn_mfma_f32_16x16x32_f16(qh[kb2], xh0b, a01, 0, 0, 0);
            a11 = __builtin_amdgcn_mfma_f32_16x16x32_f16(qh[kb2], xh1b, a11, 0, 0, 0);
        }
        __syncthreads();   // all waves done reading x; safe to alias dt
        // epilogue: d = (qq - 2S) + xx -> dt
        {
            float xx0 = sm.k.xxs[m];
            float xx1 = sm.k.xxs[16 + m];
            int qb = w * 16 + quad * 4;
#pragma unroll
            for (int reg = 0; reg < 4; ++reg) {
                float qq = sm.k.QQs[qb + reg];
                float S0 = a00[reg] + a01[reg];
                float S1 = a10[reg] + a11[reg];
                sm.k.u.dt[qb + reg][m]      = (qq - 2.0f * S0) + xx0;
                sm.k.u.dt[qb + reg][16 + m] = (qq - 2.0f * S1) + xx1;
            }
        }
        __syncthreads();
        // selection: thread t (<128) owns query t
        if (t < 128) {
            const int ibase = segbase + ct * 32;
            for (int j = 0; j < 32; ++j) {
                float d = sm.k.u.dt[t][j];
                if (d < sd[15]) {
                    sd[15] = d; si[15] = ibase + j;
#pragma unroll
                    for (int rr = 15; rr > 0; --rr) {
                        if (sd[rr] < sd[rr - 1]) {
                            float td2 = sd[rr]; sd[rr] = sd[rr - 1]; sd[rr - 1] = td2;
                            int ti = si[rr]; si[rr] = si[rr - 1]; si[rr - 1] = ti;
                        }
                    }
                }
            }
        }
    }
    if (t < 128) {
        size_t o = ((size_t)(qbase + t)) * 256 + slotb;
#pragma unroll
        for (int rr = 0; rr < 16; ++rr) { PD[o + rr] = sd[rr]; PI[o + rr] = si[rr]; }
    }
}

template <typename SM>
__device__ __forceinline__ void merge_body(
        SM& sm, const float* __restrict__ PD, const int* __restrict__ PI,
        int* __restrict__ NN, int t, int qg, int SH) {
    const int ENT = 1 << SH;
    for (int i2 = t; i2 < (16 << SH); i2 += 512) {
        int qi = i2 >> SH, j = i2 & (ENT - 1);
        sm.m.ld[qi][j] = PD[(size_t)(qg + qi) * 256 + j];
        sm.m.li[qi][j] = PI[(size_t)(qg + qi) * 256 + j];
    }
    __syncthreads();
    if (t < 16) {
        float sd[16]; int si[16];
#pragma unroll
        for (int rr = 0; rr < 16; ++rr) { sd[rr] = __builtin_inff(); si[rr] = 0x7fffffff; }
        // slot-major ascending = ascending global candidate index; strict-<
        // insertion keeps lowest index on ties (= lax.top_k).
        for (int j = 0; j < ENT; ++j) {
            float d = sm.m.ld[t][j];
            if (d < sd[15]) {
                sd[15] = d; si[15] = sm.m.li[t][j];
#pragma unroll
                for (int rr = 15; rr > 0; --rr) {
                    if (sd[rr] < sd[rr - 1]) {
                        float td2 = sd[rr]; sd[rr] = sd[rr - 1]; sd[rr - 1] = td2;
                        int ti = si[rr]; si[rr] = si[rr - 1]; si[rr - 1] = ti;
                    }
                }
            }
        }
        int og = (qg + t) * TD_K;
#pragma unroll
        for (int rr = 0; rr < 16; ++rr) NN[og + rr] = si[rr];
    }
}

template <typename SM>
__device__ __forceinline__ void maxp_body(
        SM& sm, const unsigned short* __restrict__ H, const int* __restrict__ NN,
        const float* __restrict__ SS, float* __restrict__ outF, int t, int q0) {
    if (t < 256) sm.mp.nbr[t] = NN[(size_t)q0 * 16 + t];
    __syncthreads();
    const int hq = t >> 8, tc = t & 255;
    float sc0 = SS[2 * tc], sc1 = SS[2 * tc + 1];
    float sh0 = SS[512 + 2 * tc], sh1 = SS[512 + 2 * tc + 1];
#pragma unroll
    for (int qi = 0; qi < 8; ++qi) {
        const int q = hq * 8 + qi;
        float m0 = 0.0f, m1 = 0.0f;   // relu floor
#pragma unroll
        for (int kk = 0; kk < 16; ++kk) {
            int row = sm.mp.nbr[q * 16 + kk];
            unsigned u = ((const unsigned*)(H + (size_t)row * 512))[tc];
            float lo = __uint_as_float(u << 16);
            float hi = __uint_as_float(u & 0xffff0000u);
            m0 = fmaxf(m0, fmaf(sc0, lo, sh0));
            m1 = fmaxf(m1, fmaf(sc1, hi, sh1));
        }
        float2 o; o.x = m0; o.y = m1;
        *(float2*)&outF[(size_t)(q0 + q) * 512 + 2 * tc] = o;
    }
}

// ---------------------------------------------------------------------------
// K1: FPS (private CUs) + everything not dependent on FPS completion.
// ---------------------------------------------------------------------------
__global__ __launch_bounds__(512)
void td_main(const float* __restrict__ feat, const float* __restrict__ pos,
             const float* __restrict__ W, const float* __restrict__ bias,
             const float* __restrict__ gamma, const float* __restrict__ beta,
             unsigned short* __restrict__ H, int* __restrict__ FPSI,
             int* __restrict__ NN, float* __restrict__ P1, float* __restrict__ P2,
             float* __restrict__ SS, float* __restrict__ PD, int* __restrict__ PI,
             float* __restrict__ outF, float* __restrict__ outP,
             float* __restrict__ outB, int* __restrict__ flags) {
    __shared__ SmU1 sm;
    const int bx = blockIdx.x;
    const int t  = threadIdx.x;

    if (bx < 16) {
        // ================= FPS: round-0 core, 256 active threads =============
        __builtin_amdgcn_s_setprio(2);
        const int b = bx;
        const int w = t >> 6;
        v2f px[8], py[8], pz[8], md[8];
        int ni0[8], ni1[8];
        float lx = 0.0f, ly = 0.0f, lz = 0.0f;
        if (t < 256) {
#pragma unroll
            for (int j = 0; j < 8; ++j) {
                int p0 = j * 512 + t, p1 = p0 + 256;
                const float* q0 = pos + (size_t)(b * TD_P + p0) * 3;
                const float* q1 = pos + (size_t)(b * TD_P + p1) * 3;
                float x0 = q0[0], y0 = q0[1], z0 = q0[2];
                float x1 = q1[0], y1 = q1[1], z1 = q1[2];
                px[j] = (v2f){x0, x1}; py[j] = (v2f){y0, y1}; pz[j] = (v2f){z0, z1};
                sm.f.p4[p0] = make_float4(x0, y0, z0, 0.0f);
                sm.f.p4[p1] = make_float4(x1, y1, z1, 0.0f);
                md[j] = (v2f){__builtin_inff(), __builtin_inff()};
                ni0[j] = ~p0; ni1[j] = ~p1;
            }
            if (t == 0) sm.f.sel[0] = 0;
        }
        __syncthreads();
        if (t < 256) { float4 wp = sm.f.p4[0]; lx = wp.x; ly = wp.y; lz = wp.z; }
        for (int s = 0; s < TD_S - 1; ++s) {
            const int par = s & 1;
            if (t < 256) {
                double k[16];
                {
#pragma clang fp contract(off)
                    v2f l2x = (v2f){lx, lx}, l2y = (v2f){ly, ly}, l2z = (v2f){lz, lz};
#pragma unroll
                    for (int j = 0; j < 8; ++j) {
                        v2f dx = px[j] - l2x;
                        v2f dy = py[j] - l2y;
                        v2f dz = pz[j] - l2z;
                        v2f sx = dx * dx;
                        v2f sy = dy * dy;
                        v2f sz = dz * dz;
                        v2f dd = (sx + sy) + sz;
                        md[j] = __builtin_elementwise_min(md[j], dd);
                        k[2 * j]     = __hiloint2double(__float_as_int(md[j].x), ni0[j]);
                        k[2 * j + 1] = __hiloint2double(__float_as_int(md[j].y), ni1[j]);
                    }
                }
#pragma unroll
                for (int st = 8; st > 0; st >>= 1)
#pragma unroll
                    for (int i = 0; i < st; ++i) k[i] = fmax(k[i], k[i + st]);
                double tk = k[0];
                TD_DPPSTEPD(tk, 0x111, true)    // row_shr:1
                TD_DPPSTEPD(tk, 0x112, true)    // row_shr:2
                TD_DPPSTEPD(tk, 0x114, true)    // row_shr:4
                TD_DPPSTEPD(tk, 0x118, true)    // row_shr:8
                TD_DPPSTEPD(tk, 0x142, false)   // row_bcast:15
                TD_DPPSTEPD(tk, 0x143, false)   // row_bcast:31
                if ((t & 63) == 63)
                    sm.f.kw[par][w] = (unsigned long long)__double_as_longlong(tk);
            }
            __syncthreads();
            if (t < 256) {
                const double2* kd = (const double2*)sm.f.kw[par];
                double2 va = kd[0], vb = kd[1];
                double gk = fmax(fmax(va.x, va.y), fmax(vb.x, vb.y));
                unsigned idx = ~(unsigned)__double2loint(gk);
                if (t == 0) sm.f.sel[s + 1] = (int)idx;
                float4 wp = sm.f.p4[idx];
                lx = wp.x; ly = wp.y; lz = wp.z;
            }
            // publish chunk c = samples [c*128,(c+1)*128) (wave 0 only).
            if (t < 64 && (s & 127) == 127 && s < 896) {
                int c = s >> 7;
                int i0 = c * 128 + 2 * t;
                FPSI[b * TD_S + i0]     = b * TD_P + sm.f.sel[i0];
                FPSI[b * TD_S + i0 + 1] = b * TD_P + sm.f.sel[i0 + 1];
                __threadfence();
                if (t == 0) add_rel(flags + F_CHUNKREADY + c, 1);
            }
        }
        __syncthreads();
        for (int s = t; s < TD_S; s += 512) {
            int li = sm.f.sel[s];
            int og = b * TD_S + s;
            float4 wp = sm.f.p4[li];
            outP[og * 3 + 0] = wp.x;
            outP[og * 3 + 1] = wp.y;
            outP[og * 3 + 2] = wp.z;
            outB[og] = (float)b;
            FPSI[og] = b * TD_P + li;
        }
    } else if (bx < 1040) {
        // ================= MLP GEMM: 256x128 tile, 8x8 micro =================
        const int gb = bx - 16;
        const int mb = gb >> 2, nb = gb & 3;
        const int tm = t >> 4, tn = t & 15;
        float acc[8][8];
#pragma unroll
        for (int i = 0; i < 8; ++i)
#pragma unroll
            for (int j = 0; j < 8; ++j) acc[i][j] = 0.0f;
        float* As = sm.g.As;
        float* Bs = sm.g.Bs;
        for (int kc = 0; kc < 16; ++kc) {
#pragma unroll
            for (int p2 = 0; p2 < 2; ++p2) {
                int f4 = t + 512 * p2;
                int r = f4 >> 2, c4 = f4 & 3;
                float4 v = *(const float4*)&feat[(size_t)(mb * 256 + r) * 256 + kc * 16 + c4 * 4];
                As[(c4 * 4 + 0) * 260 + r] = v.x;
                As[(c4 * 4 + 1) * 260 + r] = v.y;
                As[(c4 * 4 + 2) * 260 + r] = v.z;
                As[(c4 * 4 + 3) * 260 + r] = v.w;
            }
            {
                int kk = t >> 5, n4 = t & 31;
                float4 v = *(const float4*)&W[(size_t)(kc * 16 + kk) * 512 + nb * 128 + n4 * 4];
                *(float4*)&Bs[kk * 128 + n4 * 4] = v;
            }
            __syncthreads();
#pragma unroll
            for (int kk = 0; kk < 16; ++kk) {
                float4 a0 = *(float4*)&As[kk * 260 + tm * 8];
                float4 a1 = *(float4*)&As[kk * 260 + tm * 8 + 4];
                float4 b0 = *(float4*)&Bs[kk * 128 + tn * 8];
                float4 b1 = *(float4*)&Bs[kk * 128 + tn * 8 + 4];
                float av[8] = {a0.x, a0.y, a0.z, a0.w, a1.x, a1.y, a1.z, a1.w};
                float bv2[8] = {b0.x, b0.y, b0.z, b0.w, b1.x, b1.y, b1.z, b1.w};
#pragma unroll
                for (int i = 0; i < 8; ++i)
#pragma unroll
                    for (int j = 0; j < 8; ++j)
                        acc[i][j] = fmaf(av[i], bv2[j], acc[i][j]);
            }
            __syncthreads();
        }
        float4 bb0 = *(const float4*)&bias[nb * 128 + tn * 8];
        float4 bb1 = *(const float4*)&bias[nb * 128 + tn * 8 + 4];
        float bsv[8] = {bb0.x, bb0.y, bb0.z, bb0.w, bb1.x, bb1.y, bb1.z, bb1.w};
#pragma unroll
        for (int i = 0; i < 8; ++i) {
            int row = mb * 256 + tm * 8 + i;
            uint4 pk;
            pk.x = (unsigned)f2bf(acc[i][0] + bsv[0]) | ((unsigned)f2bf(acc[i][1] + bsv[1]) << 16);
            pk.y = (unsigned)f2bf(acc[i][2] + bsv[2]) | ((unsigned)f2bf(acc[i][3] + bsv[3]) << 16);
            pk.z = (unsigned)f2bf(acc[i][4] + bsv[4]) | ((unsigned)f2bf(acc[i][5] + bsv[5]) << 16);
            pk.w = (unsigned)f2bf(acc[i][6] + bsv[6]) | ((unsigned)f2bf(acc[i][7] + bsv[7]) << 16);
            *(uint4*)&H[(size_t)row * 512 + nb * 128 + tn * 8] = pk;
        }
        __syncthreads();
        if (t == 0) { __threadfence(); add_rel(flags + F_GEMMDONE, 1); }
    } else if (bx < 1936) {
        // ================= KNN chunks 0..6: 128q x 512c ======================
        const int kb = bx - 1040;
        const int c = kb >> 7, ii = kb & 127;
        const int b = ii & 15, s = ii >> 4;          // s in [0,8)
        if (t == 0) {
            while (ld_acq(flags + F_CHUNKREADY + c) < 16) __builtin_amdgcn_s_sleep(16);
        }
        __syncthreads();
        knn_body(sm, feat, FPSI, PD, PI, t,
                 b * TD_S + c * 128, b * TD_P + s * 512, 16, s * 16);
        __syncthreads();
        if (t == 0) { __threadfence(); add_rel(flags + F_KNNDONE + c, 1); }
    } else if (bx < 2192) {
        // ================= BN partial sums (needs all GEMM) ==================
        const int rb = bx - 1936;
        if (t == 0) {
            while (ld_acq(flags + F_GEMMDONE) < 1024) __builtin_amdgcn_s_sleep(32);
        }
        __syncthreads();
        if (t < 256) {
            float s1a = 0, s2a = 0, s1b = 0, s2b = 0;
            for (int r = 0; r < 256; ++r) {
                const unsigned* hp = (const unsigned*)(H + (size_t)(rb * 256 + r) * 512);
                unsigned u = hp[t];
                float lo = __uint_as_float(u << 16);
                float hi = __uint_as_float(u & 0xffff0000u);
                s1a += lo; s2a = fmaf(lo, lo, s2a);
                s1b += hi; s2b = fmaf(hi, hi, s2b);
            }
            P1[rb * 512 + 2 * t] = s1a; P1[rb * 512 + 2 * t + 1] = s1b;
            P2[rb * 512 + 2 * t] = s2a; P2[rb * 512 + 2 * t + 1] = s2b;
        }
        __syncthreads();
        if (t == 0) { __threadfence(); add_rel(flags + F_STATSDONE, 1); }
    } else if (bx == 2192) {
        // ================= BN finalize -> scale/shift ========================
        if (t == 0) {
            while (ld_acq(flags + F_STATSDONE) < 256) __builtin_amdgcn_s_sleep(32);
        }
        __syncthreads();
        {
            const int ch = t;
            float s1 = 0, s2 = 0;
            for (int rb2 = 0; rb2 < 256; ++rb2) {
                s1 += P1[rb2 * 512 + ch]; s2 += P2[rb2 * 512 + ch];
            }
            const float invN = 1.0f / 65536.0f;
            float mu  = s1 * invN;
            float var = s2 * invN - mu * mu;
            float sc  = gamma[ch] * (1.0f / sqrtf(var + 1e-5f));
            float sh  = beta[ch] - mu * sc;
            SS[ch] = sc; SS[512 + ch] = sh;
        }
        __syncthreads();
        if (t == 0) { __threadfence(); st_rel(flags + F_BNFIN, 1); }
    } else if (bx < 2833) {
        // ================= merge chunks 0..4: 16q, 128 slots =================
        const int md = bx - 2193;
        const int c = md >> 7, ii = md & 127;
        const int b = ii & 15, g8 = ii >> 4;
        if (t == 0) {
            while (ld_acq(flags + F_KNNDONE + c) < 128) __builtin_amdgcn_s_sleep(16);
        }
        __syncthreads();
        merge_body(sm, PD, PI, NN, t, b * TD_S + c * 128 + g8 * 16, 7);
        __syncthreads();
        if (t == 0) { __threadfence(); add_rel(flags + F_MERGEDONE + c, 1); }
    } else {
        // ================= maxpool chunks 0..4: 16q ==========================
        const int pd2 = bx - 2833;
        const int c = pd2 >> 7, ii = pd2 & 127;
        const int b = ii & 15, g = ii >> 4;
        if (t == 0) {
            while (ld_acq(flags + F_MERGEDONE + c) < 128) __builtin_amdgcn_s_sleep(16);
            while (ld_acq(flags + F_BNFIN) < 1) __builtin_amdgcn_s_sleep(16);
        }
        __syncthreads();
        maxp_body(sm, H, NN, SS, outF, t, b * TD_S + c * 128 + g * 16);
    }
}

// ---------------------------------------------------------------------------
// K2: FPS-end-dependent remainder at 2 blocks/CU (no FPS pad).
// ---------------------------------------------------------------------------
__global__ __launch_bounds__(512)
void td_tail(const float* __restrict__ feat, const unsigned short* __restrict__ H,
             const int* __restrict__ FPSI, int* __restrict__ NN,
             const float* __restrict__ SS, float* __restrict__ PD,
             int* __restrict__ PI, float* __restrict__ outF,
             int* __restrict__ flags) {
    __shared__ SmU2 sm;
    const int bx = blockIdx.x;
    const int t  = threadIdx.x;

    if (bx < 256) {
        // ================= KNN chunk 7: 128q x 256c ==========================
        const int b = bx & 15, s = bx >> 4;          // s in [0,16)
        knn_body(sm, feat, FPSI, PD, PI, t,
                 b * TD_S + 896, b * TD_P + s * 256, 8, s * 16);
        __syncthreads();
        if (t == 0) { __threadfence(); add_rel(flags + F_KNNDONE + 7, 1); }
    } else if (bx < 640) {
        // ================= merge chunks 5,6,7 ================================
        const int md = bx - 256;
        const int c = 5 + (md >> 7), ii = md & 127;
        const int b = ii & 15, g8 = ii >> 4;
        if (c == 7 && t == 0) {
            while (ld_acq(flags + F_KNNDONE + 7) < 256) __builtin_amdgcn_s_sleep(16);
        }
        __syncthreads();
        merge_body(sm, PD, PI, NN, t, b * TD_S + c * 128 + g8 * 16, (c < 7) ? 7 : 8);
        __syncthreads();
        if (t == 0) { __threadfence(); add_rel(flags + F_MERGEDONE + c, 1); }
    } else {
        // ================= maxpool chunks 5,6,7 ==============================
        const int pd2 = bx - 640;
        const int c = 5 + (pd2 >> 7), ii = pd2 & 127;
        const int b = ii & 15, g = ii >> 4;
        if (t == 0) {
            while (ld_acq(flags + F_MERGEDONE + c) < 128) __builtin_amdgcn_s_sleep(16);
        }
        __syncthreads();
        maxp_body(sm, H, NN, SS, outF, t, b * TD_S + c * 128 + g * 16);
    }
}

extern "C" void kernel_launch(void* const* d_in, const int* in_sizes, int n_in,
                              void* d_out, int out_size, void* d_ws, size_t ws_size,
                              hipStream_t stream) {
    const float* feat  = (const float*)d_in[0];
    const float* pos   = (const float*)d_in[1];
    // d_in[2] = batch (int32): unused, value is row/P by construction
    const float* W     = (const float*)d_in[3];
    const float* bias  = (const float*)d_in[4];
    const float* gamma = (const float*)d_in[5];
    const float* beta  = (const float*)d_in[6];

    char* ws = (char*)d_ws;
    int* flags        = (int*)ws;                        //      4,096 B (memset)
    unsigned short* H = (unsigned short*)(ws + 4096);    // 67,108,864 B
    int*   FPSI = (int*)  (ws + 67112960);               //     65,536 B
    int*   NN   = (int*)  (ws + 67178496);               //  1,048,576 B
    float* P1   = (float*)(ws + 68227072);               //    524,288 B
    float* P2   = (float*)(ws + 68751360);               //    524,288 B
    float* SS   = (float*)(ws + 69275648);               //      4,096 B
    float* PD   = (float*)(ws + 69279744);               // 16,777,216 B
    int*   PI   = (int*)  (ws + 86056960);               // 16,777,216 B
    // end 102,834,176 B <= ws (>=146 MB proven usable in r2)

    float* outF = (float*)d_out;
    float* outP = outF + (size_t)TD_B * TD_S * TD_OUTF;
    float* outB = outP + (size_t)TD_B * TD_S * 3;

    hipMemsetAsync(flags, 0, 4096, stream);
    td_main<<<3473, 512, 0, stream>>>(feat, pos, W, bias, gamma, beta,
                                      H, FPSI, NN, P1, P2, SS, PD, PI,
                                      outF, outP, outB, flags);
    td_tail<<<1024, 512, 0, stream>>>(feat, H, FPSI, NN, SS, PD, PI, outF, flags);
}

// Round 9
// 1081.115 us; speedup vs baseline: 2.1920x; 2.1920x over previous
//
#include <hip/hip_runtime.h>
#include <cstddef>

// TransitionDown: B=16 clouds, P=4096 pts, S=1024 fps samples, K=16 knn,
// IN_F=256, OUT_F=512.
// Consolidated pipeline (r0 architecture, proven 1101us; overlap schemes of
// r2-r8 all regressed or hung). Stream-ordered kernels, no flags/spins:
//   L1 td_fused: blocks[0,16)   FPS per cloud (private CU via 84KB LDS pad),
//                blocks[16,1040) MLP GEMM fp32 -> h bf16 (FPS shadow)
//                               + fused BN partial sums (per-block, no atomics)
//   L2 td_bnfin: reduce 256 partials/ch -> scale/shift     (~15us)
//   L3 td_knn2:  fp16-split MFMA KNN, self-contained norms (~180us)
//   L4 td_merge: exact 4-way merge of segment top-16       (~20us)
//   L5 td_maxpool: gather + BN + ReLU + max over K         (~135us)

#define TD_B   16
#define TD_P   4096
#define TD_S   1024
#define TD_K   16
#define TD_INF 256
#define TD_OUTF 512

typedef __attribute__((ext_vector_type(8))) _Float16 half8;
typedef __attribute__((ext_vector_type(4))) float    f32x4;
typedef __attribute__((ext_vector_type(2))) float    v2f;

__device__ __forceinline__ unsigned short f2bf(float x) {
    unsigned u = __float_as_uint(x);
    unsigned r = (u + 0x7fffu + ((u >> 16) & 1u)) >> 16;   // RNE
    return (unsigned short)r;
}

struct FpsSm {
    float4 p4[TD_P];      // 64 KB: (x,y,z,-) per point, b128 winner read
    int    sel[TD_S];
    unsigned long long kw[2][8];   // parity-buffered per-wave argmax keys
};
struct GemmSm {
    float As[16 * 260];   // [k][m]; reused as red[32][128] for stats reduce
    float Bs[16 * 128];   // [k][n]
};
union SmU {
    FpsSm f; GemmSm g;
    char pad_[84000];     // 1 block/CU: FPS keeps a private CU (r0-proven)
};

// One level of a wave64 max-reduce on a u64 key via paired 32-bit DPP +
// 64-bit compare. Result valid in lane 63 after shr 1,2,4,8 + bcast15 + bcast31.
#define TD_DPPSTEP(k, ctl, bc)                                                          \
    {                                                                                   \
        unsigned yh_ = (unsigned)__builtin_amdgcn_update_dpp(                           \
            0, (int)(unsigned)((k) >> 32), (ctl), 0xf, 0xf, (bc));                      \
        unsigned yl_ = (unsigned)__builtin_amdgcn_update_dpp(                           \
            0, (int)(unsigned)(k), (ctl), 0xf, 0xf, (bc));                              \
        unsigned long long y_ = ((unsigned long long)yh_ << 32) | yl_;                  \
        if (y_ > (k)) (k) = y_;                                                         \
    }

__global__ __launch_bounds__(512)
void td_fused(const float* __restrict__ feat, const float* __restrict__ pos,
              const float* __restrict__ W, const float* __restrict__ bias,
              unsigned short* __restrict__ H, int* __restrict__ FPSI,
              float* __restrict__ outP, float* __restrict__ outB,
              float* __restrict__ P1p, float* __restrict__ P2p) {
    __shared__ SmU sm;
    const int bx = blockIdx.x;
    const int t  = threadIdx.x;

    if (bx < 16) {
        // ---------------- FPS: one block per cloud, private CU ---------------
        // Only t<256 active (1 wave/SIMD owns the full issue port); 16 pts per
        // thread as 8 packed v2f lanes (v_pk_* fp32, contract off => np-bitwise
        // sub,sq,sq,sq,add,add,min per element). key = u64(hi=fp32 bits of
        // min_d, lo=~p): max => largest d, tie -> lowest p.
        __builtin_amdgcn_s_setprio(2);
        const int b = bx;
        const int w = t >> 6;
        v2f px[8], py[8], pz[8], md[8];
        int ni0[8], ni1[8];
        float lx = 0.0f, ly = 0.0f, lz = 0.0f;
        if (t < 256) {
#pragma unroll
            for (int j = 0; j < 8; ++j) {
                int p0 = j * 512 + t, p1 = p0 + 256;
                const float* q0 = pos + (size_t)(b * TD_P + p0) * 3;
                const float* q1 = pos + (size_t)(b * TD_P + p1) * 3;
                float x0 = q0[0], y0 = q0[1], z0 = q0[2];
                float x1 = q1[0], y1 = q1[1], z1 = q1[2];
                px[j] = (v2f){x0, x1}; py[j] = (v2f){y0, y1}; pz[j] = (v2f){z0, z1};
                sm.f.p4[p0] = make_float4(x0, y0, z0, 0.0f);
                sm.f.p4[p1] = make_float4(x1, y1, z1, 0.0f);
                md[j] = (v2f){__builtin_inff(), __builtin_inff()};
                ni0[j] = ~p0; ni1[j] = ~p1;
            }
            if (t == 0) sm.f.sel[0] = 0;
        }
        __syncthreads();
        if (t < 256) { float4 wp = sm.f.p4[0]; lx = wp.x; ly = wp.y; lz = wp.z; }
        for (int s = 0; s < TD_S - 1; ++s) {
            const int par = s & 1;
            if (t < 256) {
                double k[16];
                {
#pragma clang fp contract(off)
                    v2f l2x = (v2f){lx, lx}, l2y = (v2f){ly, ly}, l2z = (v2f){lz, lz};
#pragma unroll
                    for (int j = 0; j < 8; ++j) {
                        v2f dx = px[j] - l2x;
                        v2f dy = py[j] - l2y;
                        v2f dz = pz[j] - l2z;
                        v2f sx = dx * dx;
                        v2f sy = dy * dy;
                        v2f sz = dz * dz;
                        v2f dd = (sx + sy) + sz;
                        md[j] = __builtin_elementwise_min(md[j], dd);
                        k[2 * j]     = __hiloint2double(__float_as_int(md[j].x), ni0[j]);
                        k[2 * j + 1] = __hiloint2double(__float_as_int(md[j].y), ni1[j]);
                    }
                }
                // in-thread tree (15 v_max_f64)
#pragma unroll
                for (int st = 8; st > 0; st >>= 1)
#pragma unroll
                    for (int i = 0; i < st; ++i) k[i] = fmax(k[i], k[i + st]);
                unsigned long long tk = (unsigned long long)__double_as_longlong(k[0]);
                TD_DPPSTEP(tk, 0x111, true)    // row_shr:1
                TD_DPPSTEP(tk, 0x112, true)    // row_shr:2
                TD_DPPSTEP(tk, 0x114, true)    // row_shr:4
                TD_DPPSTEP(tk, 0x118, true)    // row_shr:8
                TD_DPPSTEP(tk, 0x142, false)   // row_bcast:15
                TD_DPPSTEP(tk, 0x143, false)   // row_bcast:31
                if ((t & 63) == 63) sm.f.kw[par][w] = tk;
            }
            __syncthreads();
            if (t < 256) {
                const unsigned long long* kwp = sm.f.kw[par];
                double g01 = fmax(__longlong_as_double((long long)kwp[0]),
                                  __longlong_as_double((long long)kwp[1]));
                double g23 = fmax(__longlong_as_double((long long)kwp[2]),
                                  __longlong_as_double((long long)kwp[3]));
                double gk  = fmax(g01, g23);
                unsigned idx = ~(unsigned)__double2loint(gk);
                if (t == 0) sm.f.sel[s + 1] = (int)idx;
                float4 wp = sm.f.p4[idx];
                lx = wp.x; ly = wp.y; lz = wp.z;
            }
        }
        __syncthreads();
        for (int s = t; s < TD_S; s += 512) {
            int li = sm.f.sel[s];
            int og = b * TD_S + s;
            float4 wp = sm.f.p4[li];
            outP[og * 3 + 0] = wp.x;
            outP[og * 3 + 1] = wp.y;
            outP[og * 3 + 2] = wp.z;
            outB[og] = (float)b;
            FPSI[og] = b * TD_P + li;   // global row index
        }
    } else {
        // ------- MLP GEMM: 256x128 tile, 512 thr, 8x8 micro + BN partials ----
        const int gb = bx - 16;
        const int mb = gb >> 2, nb = gb & 3;
        const int tm = t >> 4, tn = t & 15;
        float acc[8][8];
#pragma unroll
        for (int i = 0; i < 8; ++i)
#pragma unroll
            for (int j = 0; j < 8; ++j) acc[i][j] = 0.0f;
        float* As = sm.g.As;
        float* Bs = sm.g.Bs;
        for (int kc = 0; kc < 16; ++kc) {
#pragma unroll
            for (int p2 = 0; p2 < 2; ++p2) {
                int f4 = t + 512 * p2;
                int r = f4 >> 2, c4 = f4 & 3;
                float4 v = *(const float4*)&feat[(size_t)(mb * 256 + r) * 256 + kc * 16 + c4 * 4];
                As[(c4 * 4 + 0) * 260 + r] = v.x;
                As[(c4 * 4 + 1) * 260 + r] = v.y;
                As[(c4 * 4 + 2) * 260 + r] = v.z;
                As[(c4 * 4 + 3) * 260 + r] = v.w;
            }
            {
                int kk = t >> 5, n4 = t & 31;
                float4 v = *(const float4*)&W[(size_t)(kc * 16 + kk) * 512 + nb * 128 + n4 * 4];
                *(float4*)&Bs[kk * 128 + n4 * 4] = v;
            }
            __syncthreads();
#pragma unroll
            for (int kk = 0; kk < 16; ++kk) {
                float4 a0 = *(float4*)&As[kk * 260 + tm * 8];
                float4 a1 = *(float4*)&As[kk * 260 + tm * 8 + 4];
                float4 b0 = *(float4*)&Bs[kk * 128 + tn * 8];
                float4 b1 = *(float4*)&Bs[kk * 128 + tn * 8 + 4];
                float av[8] = {a0.x, a0.y, a0.z, a0.w, a1.x, a1.y, a1.z, a1.w};
                float bv2[8] = {b0.x, b0.y, b0.z, b0.w, b1.x, b1.y, b1.z, b1.w};
#pragma unroll
                for (int i = 0; i < 8; ++i)
#pragma unroll
                    for (int j = 0; j < 8; ++j)
                        acc[i][j] = fmaf(av[i], bv2[j], acc[i][j]);
            }
            __syncthreads();
        }
        float4 bb0 = *(const float4*)&bias[nb * 128 + tn * 8];
        float4 bb1 = *(const float4*)&bias[nb * 128 + tn * 8 + 4];
        float bsv[8] = {bb0.x, bb0.y, bb0.z, bb0.w, bb1.x, bb1.y, bb1.z, bb1.w};
        float s1v[8], s2v[8];
#pragma unroll
        for (int j = 0; j < 8; ++j) { s1v[j] = 0.0f; s2v[j] = 0.0f; }
#pragma unroll
        for (int i = 0; i < 8; ++i) {
            int row = mb * 256 + tm * 8 + i;
            float hh[8];
#pragma unroll
            for (int j = 0; j < 8; ++j) {
                hh[j] = acc[i][j] + bsv[j];
                s1v[j] += hh[j];
                s2v[j] = fmaf(hh[j], hh[j], s2v[j]);
            }
            uint4 pk;
            pk.x = (unsigned)f2bf(hh[0]) | ((unsigned)f2bf(hh[1]) << 16);
            pk.y = (unsigned)f2bf(hh[2]) | ((unsigned)f2bf(hh[3]) << 16);
            pk.z = (unsigned)f2bf(hh[4]) | ((unsigned)f2bf(hh[5]) << 16);
            pk.w = (unsigned)f2bf(hh[6]) | ((unsigned)f2bf(hh[7]) << 16);
            *(uint4*)&H[(size_t)row * 512 + nb * 128 + tn * 8] = pk;
        }
        // BN partials: reduce s1/s2 over the 32 tm-rows -> 128 ch per block.
        // (fp32 h stats; reference computes stats in fp32 too.)
        float* red = As;   // 32*128 floats = 16 KB, fits As region
#pragma unroll
        for (int j = 0; j < 8; ++j) red[tm * 128 + tn * 8 + j] = s1v[j];
        __syncthreads();
        float r1 = 0.0f;
        if (t < 128) {
            for (int r = 0; r < 32; ++r) r1 += red[r * 128 + t];
        }
        __syncthreads();
#pragma unroll
        for (int j = 0; j < 8; ++j) red[tm * 128 + tn * 8 + j] = s2v[j];
        __syncthreads();
        if (t < 128) {
            float r2 = 0.0f;
            for (int r = 0; r < 32; ++r) r2 += red[r * 128 + t];
            P1p[mb * 512 + nb * 128 + t] = r1;
            P2p[mb * 512 + nb * 128 + t] = r2;
        }
    }
}

__global__ __launch_bounds__(512)
void td_bnfin(const float* __restrict__ P1p, const float* __restrict__ P2p,
              const float* __restrict__ gamma, const float* __restrict__ beta,
              float* __restrict__ SS) {
    const int ch = threadIdx.x;
    float s1 = 0, s2 = 0;
    for (int mb = 0; mb < 256; ++mb) {
        s1 += P1p[mb * 512 + ch];
        s2 += P2p[mb * 512 + ch];
    }
    const float invN = 1.0f / 65536.0f;
    float mu  = s1 * invN;
    float var = s2 * invN - mu * mu;
    float sc  = gamma[ch] * (1.0f / sqrtf(var + 1e-5f));
    float sh  = beta[ch] - mu * sc;
    SS[ch] = sc; SS[512 + ch] = sh;
}

// ---------------------------------------------------------------------------
// KNN via MFMA, fp16 split (hi/lo), 3-pass: S = QhXh + QhXl + QlXh.
// Grid 512 = 16 clouds x 8 q-groups(128q) x 4 candidate segments(1024c).
// Norms computed in-kernel (query: quad shuffles; candidate: during staging).
// ---------------------------------------------------------------------------
__global__ __launch_bounds__(256, 2)
void td_knn2(const float* __restrict__ feat, const int* __restrict__ FPSI,
             float* __restrict__ PD, int* __restrict__ PI) {
    __shared__ union {
        _Float16 x[2][32][264];   // [hi/lo][c][k], row pad 8 halfs
        float    dt[128][33];     // aliased after MFMA: d values [q_local][c_local]
    } sm;
    __shared__ float QQs[128];
    __shared__ int   QR[128];
    __shared__ float xxs[32];

    const int bx = blockIdx.x, t = threadIdx.x;
    const int b = bx & 15, r2 = bx >> 4;          // r2 in [0,32)
    const int qq8 = r2 >> 2, seg = r2 & 3;
    const int segbase = b * TD_P + seg * 1024;

    if (t < 128) QR[t] = FPSI[b * TD_S + qq8 * 128 + t];
    __syncthreads();

    const int w = t >> 6, lane = t & 63;
    const int m = lane & 15, quad = lane >> 4;

    // ---- Q fragments + query norms (quad-shuffle reduce) -------------------
    half8 qh[2][8], ql[2][8];
#pragma unroll
    for (int qs = 0; qs < 2; ++qs) {
        const float* qp = feat + (size_t)QR[w * 32 + qs * 16 + m] * 256;
        float qq2 = 0.0f;
#pragma unroll
        for (int ks = 0; ks < 8; ++ks) {
            float4 f0 = *(const float4*)(qp + ks * 32 + quad * 8);
            float4 f1 = *(const float4*)(qp + ks * 32 + quad * 8 + 4);
            float fv[8] = {f0.x, f0.y, f0.z, f0.w, f1.x, f1.y, f1.z, f1.w};
            half8 h, l;
#pragma unroll
            for (int j = 0; j < 8; ++j) {
                _Float16 hv = (_Float16)fv[j];
                h[j] = hv;
                l[j] = (_Float16)(fv[j] - (float)hv);
                qq2 = fmaf(fv[j], fv[j], qq2);
            }
            qh[qs][ks] = h; ql[qs][ks] = l;
        }
        qq2 += __shfl_xor(qq2, 16, 64);
        qq2 += __shfl_xor(qq2, 32, 64);
        if (quad == 0) QQs[w * 32 + qs * 16 + m] = qq2;
    }

    float sd[16]; int si[16];
#pragma unroll
    for (int r = 0; r < 16; ++r) { sd[r] = __builtin_inff(); si[r] = 0x7fffffff; }

    const int xrow = t >> 3, part = t & 7;   // staging mapping

    for (int ct = 0; ct < 32; ++ct) {
        __syncthreads();   // prev selection done reading dt (aliases x)
        // ---- stage 32 candidates x 256 k, fp32 -> fp16 hi/lo + cand norms --
        {
            const float* xp = feat + (size_t)(segbase + ct * 32 + xrow) * 256 + part * 32;
            float cn = 0.0f;
#pragma unroll
            for (int s2 = 0; s2 < 4; ++s2) {
                float4 f0 = *(const float4*)(xp + s2 * 8);
                float4 f1 = *(const float4*)(xp + s2 * 8 + 4);
                float fv[8] = {f0.x, f0.y, f0.z, f0.w, f1.x, f1.y, f1.z, f1.w};
                half8 h, l;
#pragma unroll
                for (int j = 0; j < 8; ++j) {
                    _Float16 hv = (_Float16)fv[j];
                    h[j] = hv;
                    l[j] = (_Float16)(fv[j] - (float)hv);
                    cn = fmaf(fv[j], fv[j], cn);
                }
                *(half8*)&sm.x[0][xrow][part * 32 + s2 * 8] = h;
                *(half8*)&sm.x[1][xrow][part * 32 + s2 * 8] = l;
            }
            cn += __shfl_xor(cn, 1, 64);
            cn += __shfl_xor(cn, 2, 64);
            cn += __shfl_xor(cn, 4, 64);
            if (part == 0) xxs[xrow] = cn;
        }
        __syncthreads();
        // ---- MFMA: pass-major, 4 independent acc chains --------------------
        f32x4 acc[2][2];
        acc[0][0] = (f32x4)0.0f; acc[0][1] = (f32x4)0.0f;
        acc[1][0] = (f32x4)0.0f; acc[1][1] = (f32x4)0.0f;
#pragma unroll
        for (int ks = 0; ks < 8; ++ks) {
            half8 xh0 = *(half8*)&sm.x[0][m][ks * 32 + quad * 8];
            half8 xl0 = *(half8*)&sm.x[1][m][ks * 32 + quad * 8];
            half8 xh1 = *(half8*)&sm.x[0][16 + m][ks * 32 + quad * 8];
            half8 xl1 = *(half8*)&sm.x[1][16 + m][ks * 32 + quad * 8];
            acc[0][0] = __builtin_amdgcn_mfma_f32_16x16x32_f16(ql[0][ks], xh0, acc[0][0], 0, 0, 0);
            acc[0][1] = __builtin_amdgcn_mfma_f32_16x16x32_f16(ql[0][ks], xh1, acc[0][1], 0, 0, 0);
            acc[1][0] = __builtin_amdgcn_mfma_f32_16x16x32_f16(ql[1][ks], xh0, acc[1][0], 0, 0, 0);
            acc[1][1] = __builtin_amdgcn_mfma_f32_16x16x32_f16(ql[1][ks], xh1, acc[1][1], 0, 0, 0);
            acc[0][0] = __builtin_amdgcn_mfma_f32_16x16x32_f16(qh[0][ks], xl0, acc[0][0], 0, 0, 0);
            acc[0][1] = __builtin_amdgcn_mfma_f32_16x16x32_f16(qh[0][ks], xl1, acc[0][1], 0, 0, 0);
            acc[1][0] = __builtin_amdgcn_mfma_f32_16x16x32_f16(qh[1][ks], xl0, acc[1][0], 0, 0, 0);
            acc[1][1] = __builtin_amdgcn_mfma_f32_16x16x32_f16(qh[1][ks], xl1, acc[1][1], 0, 0, 0);
            acc[0][0] = __builtin_amdgcn_mfma_f32_16x16x32_f16(qh[0][ks], xh0, acc[0][0], 0, 0, 0);
            acc[0][1] = __builtin_amdgcn_mfma_f32_16x16x32_f16(qh[0][ks], xh1, acc[0][1], 0, 0, 0);
            acc[1][0] = __builtin_amdgcn_mfma_f32_16x16x32_f16(qh[1][ks], xh0, acc[1][0], 0, 0, 0);
            acc[1][1] = __builtin_amdgcn_mfma_f32_16x16x32_f16(qh[1][ks], xh1, acc[1][1], 0, 0, 0);
        }
        __syncthreads();   // all waves done reading x; safe to alias as dt
        // ---- epilogue: d = (qq - 2S) + xx, dump to dt ----------------------
        {
            float xx0 = xxs[m];
            float xx1 = xxs[16 + m];
#pragma unroll
            for (int qs = 0; qs < 2; ++qs) {
                int qb = w * 32 + qs * 16 + quad * 4;
#pragma unroll
                for (int reg = 0; reg < 4; ++reg) {
                    float qq = QQs[qb + reg];
                    sm.dt[qb + reg][m]      = (qq - 2.0f * acc[qs][0][reg]) + xx0;
                    sm.dt[qb + reg][16 + m] = (qq - 2.0f * acc[qs][1][reg]) + xx1;
                }
            }
        }
        __syncthreads();
        // ---- selection: thread t (<128) owns query t, scans 32 candidates --
        if (t < 128) {
            const int ibase = segbase + ct * 32;
            for (int j = 0; j < 32; ++j) {
                float d = sm.dt[t][j];
                if (d < sd[15]) {
                    sd[15] = d; si[15] = ibase + j;   // ascending idx => strict < ok
#pragma unroll
                    for (int r = 15; r > 0; --r) {
                        if (sd[r] < sd[r - 1]) {
                            float td2 = sd[r]; sd[r] = sd[r - 1]; sd[r - 1] = td2;
                            int ti = si[r]; si[r] = si[r - 1]; si[r - 1] = ti;
                        }
                    }
                }
            }
        }
    }
    // ---- write sorted per-segment partial top-16 ---------------------------
    if (t < 128) {
        size_t o = ((size_t)(b * TD_S + qq8 * 128 + t)) * 64 + seg * 16;
#pragma unroll
        for (int r = 0; r < 16; ++r) { PD[o + r] = sd[r]; PI[o + r] = si[r]; }
    }
}

// Exact 4-way merge of sorted segment partials -> final top-16 per query.
__global__ __launch_bounds__(64)
void td_merge(const float* __restrict__ PD, const int* __restrict__ PI,
              int* __restrict__ NN) {
    __shared__ float ld_[64][65];
    __shared__ int   li_[64][65];
    const int bx = blockIdx.x, t = threadIdx.x;
    for (int j = 0; j < 64; ++j) {
        ld_[j][t] = PD[(size_t)bx * 4096 + j * 64 + t];
        li_[j][t] = PI[(size_t)bx * 4096 + j * 64 + t];
    }
    __syncthreads();
    int p[4] = {0, 0, 0, 0};
    int og = (bx * 64 + t) * TD_K;
    for (int r = 0; r < 16; ++r) {
        float bd = __builtin_inff(); int bi = 0x7fffffff; int bs = 0;
#pragma unroll
        for (int s = 0; s < 4; ++s) {
            if (p[s] < 16) {
                float d = ld_[t][s * 16 + p[s]];
                int   i = li_[t][s * 16 + p[s]];
                if (d < bd || (d == bd && i < bi)) { bd = d; bi = i; bs = s; }
            }
        }
        p[bs]++;
        NN[og + r] = bi;
    }
}

// 4 queries per block; cloud-grouped swizzle for L2 locality on H rows.
__global__ __launch_bounds__(256)
void td_maxpool(const unsigned short* __restrict__ H, const int* __restrict__ NN,
                const float* __restrict__ SS, float* __restrict__ outF) {
    __shared__ int nbr[64];
    const int bx = blockIdx.x, t = threadIdx.x;
    const int cloud = bx & 15, blk = bx >> 4;       // 256 blocks per cloud
    const int qbase = cloud * 1024 + blk * 4;
    if (t < 64) nbr[t] = NN[(size_t)qbase * 16 + t];
    __syncthreads();
    float sc0 = SS[2 * t], sc1 = SS[2 * t + 1];
    float sh0 = SS[512 + 2 * t], sh1 = SS[512 + 2 * t + 1];
#pragma unroll
    for (int qi = 0; qi < 4; ++qi) {
        float m0 = 0.0f, m1 = 0.0f;   // relu floor: max_k relu(v) = max(0, max_k v)
#pragma unroll
        for (int k = 0; k < 16; ++k) {
            int row = nbr[qi * 16 + k];
            unsigned u = ((const unsigned*)(H + (size_t)row * 512))[t];
            float lo = __uint_as_float(u << 16);
            float hi = __uint_as_float(u & 0xffff0000u);
            m0 = fmaxf(m0, fmaf(sc0, lo, sh0));
            m1 = fmaxf(m1, fmaf(sc1, hi, sh1));
        }
        float2 o; o.x = m0; o.y = m1;
        *(float2*)&outF[(size_t)(qbase + qi) * 512 + 2 * t] = o;
    }
}

extern "C" void kernel_launch(void* const* d_in, const int* in_sizes, int n_in,
                              void* d_out, int out_size, void* d_ws, size_t ws_size,
                              hipStream_t stream) {
    const float* feat  = (const float*)d_in[0];
    const float* pos   = (const float*)d_in[1];
    // d_in[2] = batch (int32): unused, value is row/P by construction
    const float* W     = (const float*)d_in[3];
    const float* bias  = (const float*)d_in[4];
    const float* gamma = (const float*)d_in[5];
    const float* beta  = (const float*)d_in[6];

    char* ws = (char*)d_ws;
    unsigned short* H = (unsigned short*)ws;            // 67,108,864 B (bf16 h)
    int*   FPSI= (int*)  (ws + 67108864);               //     65,536 B
    int*   NN  = (int*)  (ws + 67174400);               //  1,048,576 B
    float* P1p = (float*)(ws + 68222976);               //    524,288 B
    float* P2p = (float*)(ws + 68747264);               //    524,288 B
    float* SS  = (float*)(ws + 69271552);               //      4,096 B
    float* PD  = (float*)(ws + 69275648);               //  4,194,304 B
    int*   PI  = (int*)  (ws + 73469952);               //  4,194,304 B

    float* outF = (float*)d_out;
    float* outP = outF + (size_t)TD_B * TD_S * TD_OUTF;   // 8,388,608
    float* outB = outP + (size_t)TD_B * TD_S * 3;         // +49,152

    td_fused  <<<1040, 512, 0, stream>>>(feat, pos, W, bias, H, FPSI, outP, outB, P1p, P2p);
    td_bnfin  <<<1, 512, 0, stream>>>(P1p, P2p, gamma, beta, SS);
    td_knn2   <<<512, 256, 0, stream>>>(feat, FPSI, PD, PI);
    td_merge  <<<256, 64, 0, stream>>>(PD, PI, NN);
    td_maxpool<<<TD_B * 256, 256, 0, stream>>>(H, NN, SS, outF);
}

// Round 10
// 1043.375 us; speedup vs baseline: 2.2713x; 1.0362x over previous
//
#include <hip/hip_runtime.h>
#include <cstddef>

// TransitionDown: B=16 clouds, P=4096 pts, S=1024 fps samples, K=16 knn,
// IN_F=256, OUT_F=512.
// Consolidated 3-kernel pipeline (r9 architecture, proven 1081us):
//   L1 td_fused: blocks[0,16)   FPS per cloud (private CU via 84KB LDS pad),
//                               fmax-DPP argmax (shorter serial chain)
//                blocks[16,1040) MLP GEMM fp32 -> h bf16 (FPS shadow)
//                               + fused BN partial sums (per-block, no atomics)
//   L2 td_knn2:  fp16-split MFMA KNN, self-contained norms; block 512 does
//                the BN finalize (scale/shift) in parallel with KNN
//   L3 td_maxpool: 4-way exact merge of segment top-16 (folded from td_merge)
//                + gather + BN + ReLU + max over K
// Overlap schemes (flags/persistent workers, r2-r8) all regressed or hung;
// stream-ordered kernels with the FPS-shadowed GEMM are the proven optimum.

#define TD_B   16
#define TD_P   4096
#define TD_S   1024
#define TD_K   16
#define TD_INF 256
#define TD_OUTF 512

typedef __attribute__((ext_vector_type(8))) _Float16 half8;
typedef __attribute__((ext_vector_type(4))) float    f32x4;
typedef __attribute__((ext_vector_type(2))) float    v2f;

__device__ __forceinline__ unsigned short f2bf(float x) {
    unsigned u = __float_as_uint(x);
    unsigned r = (u + 0x7fffu + ((u >> 16) & 1u)) >> 16;   // RNE
    return (unsigned short)r;
}

struct FpsSm {
    float4 p4[TD_P];      // 64 KB: (x,y,z,-) per point, b128 winner read
    int    sel[TD_S];
    unsigned long long kw[2][8];   // parity-buffered per-wave argmax keys
};
struct GemmSm {
    float As[16 * 260];   // [k][m]; reused as red[32][128] for stats reduce
    float Bs[16 * 128];   // [k][n]
};
union SmU {
    FpsSm f; GemmSm g;
    char pad_[84000];     // 1 block/CU: FPS keeps a private CU (r0-proven)
};

// One level of a wave64 max-reduce on a positive-double key via paired 32-bit
// DPP + v_max_f64 (key hi=fp32 bits of min_d (>=0, never NaN pattern),
// lo=~idx; positive finite doubles => fmax == bitwise u64 max, tie -> lowest
// idx). Result valid in lane 63 after shr 1,2,4,8 + bcast15 + bcast31.
// (fmax form proven correct in r3/r4/r5/r8 passing runs; ~3 fewer insts per
// level than the u64-compare form => shorter serial chain.)
#define TD_DPPSTEPD(kd_, ctl, bc)                                                       \
    {                                                                                   \
        long long ki_ = __double_as_longlong(kd_);                                      \
        unsigned yh_ = (unsigned)__builtin_amdgcn_update_dpp(                           \
            0, (int)((unsigned long long)ki_ >> 32), (ctl), 0xf, 0xf, (bc));            \
        unsigned yl_ = (unsigned)__builtin_amdgcn_update_dpp(                           \
            0, (int)(unsigned)(unsigned long long)ki_, (ctl), 0xf, 0xf, (bc));          \
        kd_ = fmax(kd_, __hiloint2double((int)yh_, (int)yl_));                          \
    }

__global__ __launch_bounds__(512)
void td_fused(const float* __restrict__ feat, const float* __restrict__ pos,
              const float* __restrict__ W, const float* __restrict__ bias,
              unsigned short* __restrict__ H, int* __restrict__ FPSI,
              float* __restrict__ outP, float* __restrict__ outB,
              float* __restrict__ P1p, float* __restrict__ P2p) {
    __shared__ SmU sm;
    const int bx = blockIdx.x;
    const int t  = threadIdx.x;

    if (bx < 16) {
        // ---------------- FPS: one block per cloud, private CU ---------------
        // Only t<256 active (1 wave/SIMD owns the full issue port); 16 pts per
        // thread as 8 packed v2f lanes (v_pk_* fp32, contract off => np-bitwise
        // sub,sq,sq,sq,add,add,min per element). key = double(hi=fp32 bits of
        // min_d, lo=~p): fmax => largest d, tie -> lowest p.
        __builtin_amdgcn_s_setprio(2);
        const int b = bx;
        const int w = t >> 6;
        v2f px[8], py[8], pz[8], md[8];
        int ni0[8], ni1[8];
        float lx = 0.0f, ly = 0.0f, lz = 0.0f;
        if (t < 256) {
#pragma unroll
            for (int j = 0; j < 8; ++j) {
                int p0 = j * 512 + t, p1 = p0 + 256;
                const float* q0 = pos + (size_t)(b * TD_P + p0) * 3;
                const float* q1 = pos + (size_t)(b * TD_P + p1) * 3;
                float x0 = q0[0], y0 = q0[1], z0 = q0[2];
                float x1 = q1[0], y1 = q1[1], z1 = q1[2];
                px[j] = (v2f){x0, x1}; py[j] = (v2f){y0, y1}; pz[j] = (v2f){z0, z1};
                sm.f.p4[p0] = make_float4(x0, y0, z0, 0.0f);
                sm.f.p4[p1] = make_float4(x1, y1, z1, 0.0f);
                md[j] = (v2f){__builtin_inff(), __builtin_inff()};
                ni0[j] = ~p0; ni1[j] = ~p1;
            }
            if (t == 0) sm.f.sel[0] = 0;
        }
        __syncthreads();
        if (t < 256) { float4 wp = sm.f.p4[0]; lx = wp.x; ly = wp.y; lz = wp.z; }
        for (int s = 0; s < TD_S - 1; ++s) {
            const int par = s & 1;
            if (t < 256) {
                double k[16];
                {
#pragma clang fp contract(off)
                    v2f l2x = (v2f){lx, lx}, l2y = (v2f){ly, ly}, l2z = (v2f){lz, lz};
#pragma unroll
                    for (int j = 0; j < 8; ++j) {
                        v2f dx = px[j] - l2x;
                        v2f dy = py[j] - l2y;
                        v2f dz = pz[j] - l2z;
                        v2f sx = dx * dx;
                        v2f sy = dy * dy;
                        v2f sz = dz * dz;
                        v2f dd = (sx + sy) + sz;
                        md[j] = __builtin_elementwise_min(md[j], dd);
                        k[2 * j]     = __hiloint2double(__float_as_int(md[j].x), ni0[j]);
                        k[2 * j + 1] = __hiloint2double(__float_as_int(md[j].y), ni1[j]);
                    }
                }
                // in-thread tree (15 v_max_f64)
#pragma unroll
                for (int st = 8; st > 0; st >>= 1)
#pragma unroll
                    for (int i = 0; i < st; ++i) k[i] = fmax(k[i], k[i + st]);
                double tk = k[0];
                TD_DPPSTEPD(tk, 0x111, true)    // row_shr:1
                TD_DPPSTEPD(tk, 0x112, true)    // row_shr:2
                TD_DPPSTEPD(tk, 0x114, true)    // row_shr:4
                TD_DPPSTEPD(tk, 0x118, true)    // row_shr:8
                TD_DPPSTEPD(tk, 0x142, false)   // row_bcast:15
                TD_DPPSTEPD(tk, 0x143, false)   // row_bcast:31
                if ((t & 63) == 63)
                    sm.f.kw[par][w] = (unsigned long long)__double_as_longlong(tk);
            }
            __syncthreads();
            if (t < 256) {
                const double2* kd = (const double2*)sm.f.kw[par];
                double2 va = kd[0], vb = kd[1];
                double gk = fmax(fmax(va.x, va.y), fmax(vb.x, vb.y));
                unsigned idx = ~(unsigned)__double2loint(gk);
                if (t == 0) sm.f.sel[s + 1] = (int)idx;
                float4 wp = sm.f.p4[idx];
                lx = wp.x; ly = wp.y; lz = wp.z;
            }
        }
        __syncthreads();
        for (int s = t; s < TD_S; s += 512) {
            int li = sm.f.sel[s];
            int og = b * TD_S + s;
            float4 wp = sm.f.p4[li];
            outP[og * 3 + 0] = wp.x;
            outP[og * 3 + 1] = wp.y;
            outP[og * 3 + 2] = wp.z;
            outB[og] = (float)b;
            FPSI[og] = b * TD_P + li;   // global row index
        }
    } else {
        // ------- MLP GEMM: 256x128 tile, 512 thr, 8x8 micro + BN partials ----
        const int gb = bx - 16;
        const int mb = gb >> 2, nb = gb & 3;
        const int tm = t >> 4, tn = t & 15;
        float acc[8][8];
#pragma unroll
        for (int i = 0; i < 8; ++i)
#pragma unroll
            for (int j = 0; j < 8; ++j) acc[i][j] = 0.0f;
        float* As = sm.g.As;
        float* Bs = sm.g.Bs;
        for (int kc = 0; kc < 16; ++kc) {
#pragma unroll
            for (int p2 = 0; p2 < 2; ++p2) {
                int f4 = t + 512 * p2;
                int r = f4 >> 2, c4 = f4 & 3;
                float4 v = *(const float4*)&feat[(size_t)(mb * 256 + r) * 256 + kc * 16 + c4 * 4];
                As[(c4 * 4 + 0) * 260 + r] = v.x;
                As[(c4 * 4 + 1) * 260 + r] = v.y;
                As[(c4 * 4 + 2) * 260 + r] = v.z;
                As[(c4 * 4 + 3) * 260 + r] = v.w;
            }
            {
                int kk = t >> 5, n4 = t & 31;
                float4 v = *(const float4*)&W[(size_t)(kc * 16 + kk) * 512 + nb * 128 + n4 * 4];
                *(float4*)&Bs[kk * 128 + n4 * 4] = v;
            }
            __syncthreads();
#pragma unroll
            for (int kk = 0; kk < 16; ++kk) {
                float4 a0 = *(float4*)&As[kk * 260 + tm * 8];
                float4 a1 = *(float4*)&As[kk * 260 + tm * 8 + 4];
                float4 b0 = *(float4*)&Bs[kk * 128 + tn * 8];
                float4 b1 = *(float4*)&Bs[kk * 128 + tn * 8 + 4];
                float av[8] = {a0.x, a0.y, a0.z, a0.w, a1.x, a1.y, a1.z, a1.w};
                float bv2[8] = {b0.x, b0.y, b0.z, b0.w, b1.x, b1.y, b1.z, b1.w};
#pragma unroll
                for (int i = 0; i < 8; ++i)
#pragma unroll
                    for (int j = 0; j < 8; ++j)
                        acc[i][j] = fmaf(av[i], bv2[j], acc[i][j]);
            }
            __syncthreads();
        }
        float4 bb0 = *(const float4*)&bias[nb * 128 + tn * 8];
        float4 bb1 = *(const float4*)&bias[nb * 128 + tn * 8 + 4];
        float bsv[8] = {bb0.x, bb0.y, bb0.z, bb0.w, bb1.x, bb1.y, bb1.z, bb1.w};
        float s1v[8], s2v[8];
#pragma unroll
        for (int j = 0; j < 8; ++j) { s1v[j] = 0.0f; s2v[j] = 0.0f; }
#pragma unroll
        for (int i = 0; i < 8; ++i) {
            int row = mb * 256 + tm * 8 + i;
            float hh[8];
#pragma unroll
            for (int j = 0; j < 8; ++j) {
                hh[j] = acc[i][j] + bsv[j];
                s1v[j] += hh[j];
                s2v[j] = fmaf(hh[j], hh[j], s2v[j]);
            }
            uint4 pk;
            pk.x = (unsigned)f2bf(hh[0]) | ((unsigned)f2bf(hh[1]) << 16);
            pk.y = (unsigned)f2bf(hh[2]) | ((unsigned)f2bf(hh[3]) << 16);
            pk.z = (unsigned)f2bf(hh[4]) | ((unsigned)f2bf(hh[5]) << 16);
            pk.w = (unsigned)f2bf(hh[6]) | ((unsigned)f2bf(hh[7]) << 16);
            *(uint4*)&H[(size_t)row * 512 + nb * 128 + tn * 8] = pk;
        }
        // BN partials: reduce s1/s2 over the 32 tm-rows -> 128 ch per block.
        float* red = As;   // 32*128 floats = 16 KB, fits As region
#pragma unroll
        for (int j = 0; j < 8; ++j) red[tm * 128 + tn * 8 + j] = s1v[j];
        __syncthreads();
        float r1 = 0.0f;
        if (t < 128) {
            for (int r = 0; r < 32; ++r) r1 += red[r * 128 + t];
        }
        __syncthreads();
#pragma unroll
        for (int j = 0; j < 8; ++j) red[tm * 128 + tn * 8 + j] = s2v[j];
        __syncthreads();
        if (t < 128) {
            float r2 = 0.0f;
            for (int r = 0; r < 32; ++r) r2 += red[r * 128 + t];
            P1p[mb * 512 + nb * 128 + t] = r1;
            P2p[mb * 512 + nb * 128 + t] = r2;
        }
    }
}

// ---------------------------------------------------------------------------
// KNN via MFMA, fp16 split (hi/lo), 3-pass: S = QhXh + QhXl + QlXh.
// Blocks [0,512) = 16 clouds x 8 q-groups(128q) x 4 candidate segments(1024c).
// Block 512 = BN finalize (runs in parallel with KNN; maxpool reads SS next).
// Norms computed in-kernel (query: quad shuffles; candidate: during staging).
// ---------------------------------------------------------------------------
__global__ __launch_bounds__(256, 2)
void td_knn2(const float* __restrict__ feat, const int* __restrict__ FPSI,
             float* __restrict__ PD, int* __restrict__ PI,
             const float* __restrict__ P1p, const float* __restrict__ P2p,
             const float* __restrict__ gamma, const float* __restrict__ beta,
             float* __restrict__ SS) {
    __shared__ union {
        _Float16 x[2][32][264];   // [hi/lo][c][k], row pad 8 halfs
        float    dt[128][33];     // aliased after MFMA: d values [q_local][c_local]
    } sm;
    __shared__ float QQs[128];
    __shared__ int   QR[128];
    __shared__ float xxs[32];

    const int bx = blockIdx.x, t = threadIdx.x;
    if (bx == 512) {
        // ---- BN finalize -> scale/shift (2 channels per thread) ------------
        for (int ch = t; ch < 512; ch += 256) {
            float s1 = 0, s2 = 0;
            for (int mb = 0; mb < 256; ++mb) {
                s1 += P1p[mb * 512 + ch];
                s2 += P2p[mb * 512 + ch];
            }
            const float invN = 1.0f / 65536.0f;
            float mu  = s1 * invN;
            float var = s2 * invN - mu * mu;
            float sc  = gamma[ch] * (1.0f / sqrtf(var + 1e-5f));
            float sh  = beta[ch] - mu * sc;
            SS[ch] = sc; SS[512 + ch] = sh;
        }
        return;
    }
    const int b = bx & 15, r2 = bx >> 4;          // r2 in [0,32)
    const int qq8 = r2 >> 2, seg = r2 & 3;
    const int segbase = b * TD_P + seg * 1024;

    if (t < 128) QR[t] = FPSI[b * TD_S + qq8 * 128 + t];
    __syncthreads();

    const int w = t >> 6, lane = t & 63;
    const int m = lane & 15, quad = lane >> 4;

    // ---- Q fragments + query norms (quad-shuffle reduce) -------------------
    half8 qh[2][8], ql[2][8];
#pragma unroll
    for (int qs = 0; qs < 2; ++qs) {
        const float* qp = feat + (size_t)QR[w * 32 + qs * 16 + m] * 256;
        float qq2 = 0.0f;
#pragma unroll
        for (int ks = 0; ks < 8; ++ks) {
            float4 f0 = *(const float4*)(qp + ks * 32 + quad * 8);
            float4 f1 = *(const float4*)(qp + ks * 32 + quad * 8 + 4);
            float fv[8] = {f0.x, f0.y, f0.z, f0.w, f1.x, f1.y, f1.z, f1.w};
            half8 h, l;
#pragma unroll
            for (int j = 0; j < 8; ++j) {
                _Float16 hv = (_Float16)fv[j];
                h[j] = hv;
                l[j] = (_Float16)(fv[j] - (float)hv);
                qq2 = fmaf(fv[j], fv[j], qq2);
            }
            qh[qs][ks] = h; ql[qs][ks] = l;
        }
        qq2 += __shfl_xor(qq2, 16, 64);
        qq2 += __shfl_xor(qq2, 32, 64);
        if (quad == 0) QQs[w * 32 + qs * 16 + m] = qq2;
    }

    float sd[16]; int si[16];
#pragma unroll
    for (int r = 0; r < 16; ++r) { sd[r] = __builtin_inff(); si[r] = 0x7fffffff; }

    const int xrow = t >> 3, part = t & 7;   // staging mapping

    for (int ct = 0; ct < 32; ++ct) {
        __syncthreads();   // prev selection done reading dt (aliases x)
        // ---- stage 32 candidates x 256 k, fp32 -> fp16 hi/lo + cand norms --
        {
            const float* xp = feat + (size_t)(segbase + ct * 32 + xrow) * 256 + part * 32;
            float cn = 0.0f;
#pragma unroll
            for (int s2 = 0; s2 < 4; ++s2) {
                float4 f0 = *(const float4*)(xp + s2 * 8);
                float4 f1 = *(const float4*)(xp + s2 * 8 + 4);
                float fv[8] = {f0.x, f0.y, f0.z, f0.w, f1.x, f1.y, f1.z, f1.w};
                half8 h, l;
#pragma unroll
                for (int j = 0; j < 8; ++j) {
                    _Float16 hv = (_Float16)fv[j];
                    h[j] = hv;
                    l[j] = (_Float16)(fv[j] - (float)hv);
                    cn = fmaf(fv[j], fv[j], cn);
                }
                *(half8*)&sm.x[0][xrow][part * 32 + s2 * 8] = h;
                *(half8*)&sm.x[1][xrow][part * 32 + s2 * 8] = l;
            }
            cn += __shfl_xor(cn, 1, 64);
            cn += __shfl_xor(cn, 2, 64);
            cn += __shfl_xor(cn, 4, 64);
            if (part == 0) xxs[xrow] = cn;
        }
        __syncthreads();
        // ---- MFMA: pass-major, 4 independent acc chains --------------------
        f32x4 acc[2][2];
        acc[0][0] = (f32x4)0.0f; acc[0][1] = (f32x4)0.0f;
        acc[1][0] = (f32x4)0.0f; acc[1][1] = (f32x4)0.0f;
#pragma unroll
        for (int ks = 0; ks < 8; ++ks) {
            half8 xh0 = *(half8*)&sm.x[0][m][ks * 32 + quad * 8];
            half8 xl0 = *(half8*)&sm.x[1][m][ks * 32 + quad * 8];
            half8 xh1 = *(half8*)&sm.x[0][16 + m][ks * 32 + quad * 8];
            half8 xl1 = *(half8*)&sm.x[1][16 + m][ks * 32 + quad * 8];
            acc[0][0] = __builtin_amdgcn_mfma_f32_16x16x32_f16(ql[0][ks], xh0, acc[0][0], 0, 0, 0);
            acc[0][1] = __builtin_amdgcn_mfma_f32_16x16x32_f16(ql[0][ks], xh1, acc[0][1], 0, 0, 0);
            acc[1][0] = __builtin_amdgcn_mfma_f32_16x16x32_f16(ql[1][ks], xh0, acc[1][0], 0, 0, 0);
            acc[1][1] = __builtin_amdgcn_mfma_f32_16x16x32_f16(ql[1][ks], xh1, acc[1][1], 0, 0, 0);
            acc[0][0] = __builtin_amdgcn_mfma_f32_16x16x32_f16(qh[0][ks], xl0, acc[0][0], 0, 0, 0);
            acc[0][1] = __builtin_amdgcn_mfma_f32_16x16x32_f16(qh[0][ks], xl1, acc[0][1], 0, 0, 0);
            acc[1][0] = __builtin_amdgcn_mfma_f32_16x16x32_f16(qh[1][ks], xl0, acc[1][0], 0, 0, 0);
            acc[1][1] = __builtin_amdgcn_mfma_f32_16x16x32_f16(qh[1][ks], xl1, acc[1][1], 0, 0, 0);
            acc[0][0] = __builtin_amdgcn_mfma_f32_16x16x32_f16(qh[0][ks], xh0, acc[0][0], 0, 0, 0);
            acc[0][1] = __builtin_amdgcn_mfma_f32_16x16x32_f16(qh[0][ks], xh1, acc[0][1], 0, 0, 0);
            acc[1][0] = __builtin_amdgcn_mfma_f32_16x16x32_f16(qh[1][ks], xh0, acc[1][0], 0, 0, 0);
            acc[1][1] = __builtin_amdgcn_mfma_f32_16x16x32_f16(qh[1][ks], xh1, acc[1][1], 0, 0, 0);
        }
        __syncthreads();   // all waves done reading x; safe to alias as dt
        // ---- epilogue: d = (qq - 2S) + xx, dump to dt ----------------------
        {
            float xx0 = xxs[m];
            float xx1 = xxs[16 + m];
#pragma unroll
            for (int qs = 0; qs < 2; ++qs) {
                int qb = w * 32 + qs * 16 + quad * 4;
#pragma unroll
                for (int reg = 0; reg < 4; ++reg) {
                    float qq = QQs[qb + reg];
                    sm.dt[qb + reg][m]      = (qq - 2.0f * acc[qs][0][reg]) + xx0;
                    sm.dt[qb + reg][16 + m] = (qq - 2.0f * acc[qs][1][reg]) + xx1;
                }
            }
        }
        __syncthreads();
        // ---- selection: thread t (<128) owns query t, scans 32 candidates --
        if (t < 128) {
            const int ibase = segbase + ct * 32;
            for (int j = 0; j < 32; ++j) {
                float d = sm.dt[t][j];
                if (d < sd[15]) {
                    sd[15] = d; si[15] = ibase + j;   // ascending idx => strict < ok
#pragma unroll
                    for (int r = 15; r > 0; --r) {
                        if (sd[r] < sd[r - 1]) {
                            float td2 = sd[r]; sd[r] = sd[r - 1]; sd[r - 1] = td2;
                            int ti = si[r]; si[r] = si[r - 1]; si[r - 1] = ti;
                        }
                    }
                }
            }
        }
    }
    // ---- write sorted per-segment partial top-16 ---------------------------
    if (t < 128) {
        size_t o = ((size_t)(b * TD_S + qq8 * 128 + t)) * 64 + seg * 16;
#pragma unroll
        for (int r = 0; r < 16; ++r) { PD[o + r] = sd[r]; PI[o + r] = si[r]; }
    }
}

// 4 queries per block; exact 4-way merge of segment partials (folded from
// td_merge, tie-break (d,idx) identical), then gather + BN + ReLU + max.
// cloud = bx & 15 keeps each cloud's blocks on one XCD (round-robin %8) for
// H-slice L2 locality.
__global__ __launch_bounds__(256)
void td_maxpool(const unsigned short* __restrict__ H, const float* __restrict__ PD,
                const int* __restrict__ PI, const float* __restrict__ SS,
                float* __restrict__ outF) {
    __shared__ float ld2[4][65];
    __shared__ int   li2[4][65];
    __shared__ int   nbr[64];
    const int bx = blockIdx.x, t = threadIdx.x;
    const int cloud = bx & 15, blk = bx >> 4;       // 256 blocks per cloud
    const int qbase = cloud * 1024 + blk * 4;
    {
        int qi = t >> 6, j = t & 63;
        ld2[qi][j] = PD[(size_t)(qbase + qi) * 64 + j];
        li2[qi][j] = PI[(size_t)(qbase + qi) * 64 + j];
    }
    __syncthreads();
    if (t < 4) {
        int p[4] = {0, 0, 0, 0};
        for (int r = 0; r < 16; ++r) {
            float bd = __builtin_inff(); int bi = 0x7fffffff; int bs = 0;
#pragma unroll
            for (int s = 0; s < 4; ++s) {
                if (p[s] < 16) {
                    float d = ld2[t][s * 16 + p[s]];
                    int   i = li2[t][s * 16 + p[s]];
                    if (d < bd || (d == bd && i < bi)) { bd = d; bi = i; bs = s; }
                }
            }
            p[bs]++;
            nbr[t * 16 + r] = bi;
        }
    }
    __syncthreads();
    float sc0 = SS[2 * t], sc1 = SS[2 * t + 1];
    float sh0 = SS[512 + 2 * t], sh1 = SS[512 + 2 * t + 1];
#pragma unroll
    for (int qi = 0; qi < 4; ++qi) {
        float m0 = 0.0f, m1 = 0.0f;   // relu floor: max_k relu(v) = max(0, max_k v)
#pragma unroll
        for (int k = 0; k < 16; ++k) {
            int row = nbr[qi * 16 + k];
            unsigned u = ((const unsigned*)(H + (size_t)row * 512))[t];
            float lo = __uint_as_float(u << 16);
            float hi = __uint_as_float(u & 0xffff0000u);
            m0 = fmaxf(m0, fmaf(sc0, lo, sh0));
            m1 = fmaxf(m1, fmaf(sc1, hi, sh1));
        }
        float2 o; o.x = m0; o.y = m1;
        *(float2*)&outF[(size_t)(qbase + qi) * 512 + 2 * t] = o;
    }
}

extern "C" void kernel_launch(void* const* d_in, const int* in_sizes, int n_in,
                              void* d_out, int out_size, void* d_ws, size_t ws_size,
                              hipStream_t stream) {
    const float* feat  = (const float*)d_in[0];
    const float* pos   = (const float*)d_in[1];
    // d_in[2] = batch (int32): unused, value is row/P by construction
    const float* W     = (const float*)d_in[3];
    const float* bias  = (const float*)d_in[4];
    const float* gamma = (const float*)d_in[5];
    const float* beta  = (const float*)d_in[6];

    char* ws = (char*)d_ws;
    unsigned short* H = (unsigned short*)ws;            // 67,108,864 B (bf16 h)
    int*   FPSI= (int*)  (ws + 67108864);               //     65,536 B
    float* P1p = (float*)(ws + 67174400);               //    524,288 B
    float* P2p = (float*)(ws + 67698688);               //    524,288 B
    float* SS  = (float*)(ws + 68222976);               //      4,096 B
    float* PD  = (float*)(ws + 68227072);               //  4,194,304 B
    int*   PI  = (int*)  (ws + 72421376);               //  4,194,304 B

    float* outF = (float*)d_out;
    float* outP = outF + (size_t)TD_B * TD_S * TD_OUTF;   // 8,388,608
    float* outB = outP + (size_t)TD_B * TD_S * 3;         // +49,152

    td_fused  <<<1040, 512, 0, stream>>>(feat, pos, W, bias, H, FPSI, outP, outB, P1p, P2p);
    td_knn2   <<<513, 256, 0, stream>>>(feat, FPSI, PD, PI, P1p, P2p, gamma, beta, SS);
    td_maxpool<<<TD_B * 256, 256, 0, stream>>>(H, PD, PI, SS, outF);
}